// Round 6
// baseline (144.642 us; speedup 1.0000x reference)
//
#include <hip/hip_runtime.h>

// Node2VecSkipGram loss on MI355X — round 6.
// Layout reverted to round 4 (best: 115.6us): 32 lanes per 512B row, 2 batch
// elements per wave, product-form loss (1 log/element).
// New vs round 4: software-pipelined INDEX PREFETCH — issue iteration i+1's
// center/context/negative index loads before iteration i's row gathers +
// compute, removing one exposed HBM-latency stage per grid-stride iteration.

constexpr int NNEG = 20;
constexpr int D = 128;
constexpr int NBLOCKS = 2048;

__global__ __launch_bounds__(256) void n2v_loss_kernel(
    const int* __restrict__ center_nodes,
    const int* __restrict__ context_nodes,
    const int* __restrict__ negative_nodes,
    const float* __restrict__ center_w,
    const float* __restrict__ context_w,
    float* __restrict__ block_partials,
    int batch)
{
    const int lane    = threadIdx.x & 63;
    const int half    = lane >> 5;        // which batch element this 32-lane half owns
    const int sublane = lane & 31;        // float4 slot within the 512B row
    const int wave    = threadIdx.x >> 6;
    const int wpb     = blockDim.x >> 6;
    const int gwave   = blockIdx.x * wpb + wave;
    const int nwav    = gridDim.x * wpb;
    const int stride  = nwav * 2;

    float acc = 0.0f;

    int b = gwave * 2 + half;
    bool valid = (b < batch);

    // prologue: load indices for the first iteration
    int ci = 0, xi = 0;
    int nb[NNEG];
    if (valid) {
        ci = center_nodes[b];
        xi = context_nodes[b];
        const int4* np4 = reinterpret_cast<const int4*>(negative_nodes + (size_t)b * NNEG);
#pragma unroll
        for (int q = 0; q < 5; ++q) {
            const int4 v = np4[q];
            nb[q * 4 + 0] = v.x; nb[q * 4 + 1] = v.y;
            nb[q * 4 + 2] = v.z; nb[q * 4 + 3] = v.w;
        }
    }

    while (valid) {
        // snapshot current indices
        const int ci_c = ci, xi_c = xi;
        int nbc[NNEG];
#pragma unroll
        for (int k = 0; k < NNEG; ++k) nbc[k] = nb[k];

        // prefetch next iteration's indices (issued before the gather/compute
        // stage so their latency hides under it)
        const int b_next = b + stride;
        const bool valid_next = (b_next < batch);
        if (valid_next) {
            ci = center_nodes[b_next];
            xi = context_nodes[b_next];
            const int4* np4 = reinterpret_cast<const int4*>(negative_nodes + (size_t)b_next * NNEG);
#pragma unroll
            for (int q = 0; q < 5; ++q) {
                const int4 v = np4[q];
                nb[q * 4 + 0] = v.x; nb[q * 4 + 1] = v.y;
                nb[q * 4 + 2] = v.z; nb[q * 4 + 3] = v.w;
            }
        }

        // ---- gather + compute for the current element ----
        const float4* crow = reinterpret_cast<const float4*>(center_w  + (size_t)ci_c * D);
        const float4* xrow = reinterpret_cast<const float4*>(context_w + (size_t)xi_c * D);
        const float4  ce = crow[sublane];
        const float4  xe = xrow[sublane];

        float sc[NNEG + 1];
        sc[0] = fmaf(ce.x, xe.x, fmaf(ce.y, xe.y, fmaf(ce.z, xe.z, ce.w * xe.w)));

#pragma unroll
        for (int k = 0; k < NNEG; ++k) {
            const float4* nrow =
                reinterpret_cast<const float4*>(context_w + (size_t)nbc[k] * D);
            const float4 ne = nrow[sublane];
            sc[k + 1] = fmaf(ce.x, ne.x, fmaf(ce.y, ne.y, fmaf(ce.z, ne.z, ce.w * ne.w)));
        }

        // 21 half-wave (32-lane) butterflies
#pragma unroll
        for (int k = 0; k <= NNEG; ++k) {
            float v = sc[k];
#pragma unroll
            for (int off = 16; off > 0; off >>= 1)
                v += __shfl_xor(v, off, 64);
            sc[k] = v;
        }

        // product-form loss: 21 factors, two independent accumulators
        float p0 = 1.0f + __expf(-sc[0]);
        float p1 = 1.0f;
#pragma unroll
        for (int k = 1; k <= NNEG - 1; k += 2)   // 1,3,...,19
            p0 *= (1.0f + __expf(sc[k]));
#pragma unroll
        for (int k = 2; k <= NNEG; k += 2)       // 2,4,...,20
            p1 *= (1.0f + __expf(sc[k]));
        acc += __logf(p0 * p1);

        b = b_next;
        valid = valid_next;
    }

    // combine halves -> wave-uniform, then block reduction
    acc += __shfl_xor(acc, 32, 64);

    __shared__ float wsum[8];
    if (lane == 0) wsum[wave] = acc;
    __syncthreads();
    if (threadIdx.x == 0) {
        float s = 0.0f;
        for (int w = 0; w < wpb; ++w) s += wsum[w];
        block_partials[blockIdx.x] = s;
    }
}

__global__ __launch_bounds__(256) void n2v_reduce_kernel(
    const float* __restrict__ partials, int n, float inv_batch,
    float* __restrict__ out)
{
    __shared__ float sm[256];
    float v = 0.0f;
    for (int i = threadIdx.x; i < n; i += 256) v += partials[i];
    sm[threadIdx.x] = v;
    __syncthreads();
    for (int s = 128; s > 0; s >>= 1) {
        if (threadIdx.x < s) sm[threadIdx.x] += sm[threadIdx.x + s];
        __syncthreads();
    }
    if (threadIdx.x == 0) out[0] = sm[0] * inv_batch;
}

extern "C" void kernel_launch(void* const* d_in, const int* in_sizes, int n_in,
                              void* d_out, int out_size, void* d_ws, size_t ws_size,
                              hipStream_t stream) {
    const int*   center_nodes   = (const int*)d_in[0];
    const int*   context_nodes  = (const int*)d_in[1];
    const int*   negative_nodes = (const int*)d_in[2];
    const float* center_w       = (const float*)d_in[3];
    const float* context_w      = (const float*)d_in[4];
    float*       out            = (float*)d_out;
    const int    batch          = in_sizes[0];

    float* partials = (float*)d_ws;

    n2v_loss_kernel<<<NBLOCKS, 256, 0, stream>>>(
        center_nodes, context_nodes, negative_nodes,
        center_w, context_w, partials, batch);

    n2v_reduce_kernel<<<1, 256, 0, stream>>>(
        partials, NBLOCKS, 1.0f / (float)batch, out);
}

// Round 7
// 114.790 us; speedup vs baseline: 1.2601x; 1.2601x over previous
//
#include <hip/hip_runtime.h>

// Node2VecSkipGram loss on MI355X — round 7 (exact revert to round 4's 115.6us).
// 32 lanes per 512B row (float4/lane), 2 batch elements per wave.
// Loss collapse:  -log(sigmoid(s)+eps) - sum_k log(sigmoid(-s_k)+eps)
//   == log( (1+e^{-s}) * prod_k (1+e^{s_k}) )    (eps negligible: |s| < ~0.2)
// Tested and rejected: 8-lane/row layout (+3%), hand-pipelined index prefetch
// (+25%), both regressions — compiler schedules the simple for-loop best.

constexpr int NNEG = 20;
constexpr int D = 128;
constexpr int NBLOCKS = 2048;

__global__ __launch_bounds__(256) void n2v_loss_kernel(
    const int* __restrict__ center_nodes,
    const int* __restrict__ context_nodes,
    const int* __restrict__ negative_nodes,
    const float* __restrict__ center_w,
    const float* __restrict__ context_w,
    float* __restrict__ block_partials,
    int batch)
{
    const int lane    = threadIdx.x & 63;
    const int half    = lane >> 5;        // which batch element this 32-lane half owns
    const int sublane = lane & 31;        // float4 slot within the 512B row
    const int wave    = threadIdx.x >> 6;
    const int wpb     = blockDim.x >> 6;
    const int gwave   = blockIdx.x * wpb + wave;
    const int nwav    = gridDim.x * wpb;

    float acc = 0.0f;

    for (int b0 = gwave * 2; b0 < batch; b0 += nwav * 2) {
        const int b = b0 + half;
        float loss = 0.0f;

        if (b < batch) {
            const int ci = center_nodes[b];
            const int xi = context_nodes[b];

            const float4* crow = reinterpret_cast<const float4*>(center_w  + (size_t)ci * D);
            const float4* xrow = reinterpret_cast<const float4*>(context_w + (size_t)xi * D);
            const float4  ce = crow[sublane];
            const float4  xe = xrow[sublane];

            // negative indices: 20 ints = 80B, 16B-aligned -> 5x int4
            int nb[NNEG];
            {
                const int4* np4 = reinterpret_cast<const int4*>(negative_nodes + (size_t)b * NNEG);
#pragma unroll
                for (int q = 0; q < 5; ++q) {
                    const int4 v = np4[q];
                    nb[q * 4 + 0] = v.x; nb[q * 4 + 1] = v.y;
                    nb[q * 4 + 2] = v.z; nb[q * 4 + 3] = v.w;
                }
            }

            float sc[NNEG + 1];
            sc[0] = fmaf(ce.x, xe.x, fmaf(ce.y, xe.y, fmaf(ce.z, xe.z, ce.w * xe.w)));

#pragma unroll
            for (int k = 0; k < NNEG; ++k) {
                const float4* nrow =
                    reinterpret_cast<const float4*>(context_w + (size_t)nb[k] * D);
                const float4 ne = nrow[sublane];
                sc[k + 1] = fmaf(ce.x, ne.x, fmaf(ce.y, ne.y, fmaf(ce.z, ne.z, ce.w * ne.w)));
            }

            // 21 half-wave (32-lane) butterfly reductions
#pragma unroll
            for (int k = 0; k <= NNEG; ++k) {
                float v = sc[k];
#pragma unroll
                for (int off = 16; off > 0; off >>= 1)
                    v += __shfl_xor(v, off, 64);
                sc[k] = v;
            }

            // product-form loss: 21 terms across two independent accumulators
            //   p0: (1+e^{-sc0}) and odd  sc[1],sc[3],...,sc[19]  (11 factors)
            //   p1:              even sc[2],sc[4],...,sc[20]      (10 factors)
            float p0 = 1.0f + __expf(-sc[0]);
            float p1 = 1.0f;
#pragma unroll
            for (int k = 1; k <= NNEG - 1; k += 2)   // k = 1,3,...,19
                p0 *= (1.0f + __expf(sc[k]));
#pragma unroll
            for (int k = 2; k <= NNEG; k += 2)       // k = 2,4,...,20
                p1 *= (1.0f + __expf(sc[k]));
            loss = __logf(p0 * p1);
        }

        acc += loss;
    }

    // combine halves -> wave-uniform, then block reduction
    acc += __shfl_xor(acc, 32, 64);

    __shared__ float wsum[8];
    if (lane == 0) wsum[wave] = acc;
    __syncthreads();
    if (threadIdx.x == 0) {
        float s = 0.0f;
        for (int w = 0; w < wpb; ++w) s += wsum[w];
        block_partials[blockIdx.x] = s;
    }
}

__global__ __launch_bounds__(256) void n2v_reduce_kernel(
    const float* __restrict__ partials, int n, float inv_batch,
    float* __restrict__ out)
{
    __shared__ float sm[256];
    float v = 0.0f;
    for (int i = threadIdx.x; i < n; i += 256) v += partials[i];
    sm[threadIdx.x] = v;
    __syncthreads();
    for (int s = 128; s > 0; s >>= 1) {
        if (threadIdx.x < s) sm[threadIdx.x] += sm[threadIdx.x + s];
        __syncthreads();
    }
    if (threadIdx.x == 0) out[0] = sm[0] * inv_batch;
}

extern "C" void kernel_launch(void* const* d_in, const int* in_sizes, int n_in,
                              void* d_out, int out_size, void* d_ws, size_t ws_size,
                              hipStream_t stream) {
    const int*   center_nodes   = (const int*)d_in[0];
    const int*   context_nodes  = (const int*)d_in[1];
    const int*   negative_nodes = (const int*)d_in[2];
    const float* center_w       = (const float*)d_in[3];
    const float* context_w      = (const float*)d_in[4];
    float*       out            = (float*)d_out;
    const int    batch          = in_sizes[0];

    float* partials = (float*)d_ws;

    n2v_loss_kernel<<<NBLOCKS, 256, 0, stream>>>(
        center_nodes, context_nodes, negative_nodes,
        center_w, context_w, partials, batch);

    n2v_reduce_kernel<<<1, 256, 0, stream>>>(
        partials, NBLOCKS, 1.0f / (float)batch, out);
}